// Round 18
// baseline (150.161 us; speedup 1.0000x reference)
//
#include <hip/hip_runtime.h>
#include <math.h>

// ---------------------------------------------------------------------------
// 2-layer GCN (PyG GCNConv) on MI355X — tiled-partition CSR + MLP-deep gather.
// This round: dependency break + launch fusion. g1 stored UNSCALED (gemm no
// longer needs dinv) -> gemm fused into the tileHist launch (overlaps sort);
// gather1 applies dinv[src] at gather time (L2-resident 400KB lookup, fma).
// Scan collapsed to 2 launches. 7 launches total (was 9).
// out[i] = logsoftmax( dinv[i]*(g2[i] + sum_{e:dst=i} g2[src_e]) + b2 )
// g2 = dinv*( relu( dinv*(g1[i]+sum g1[src]) + b1 ) @ W2 ), g1 = (x@W1)*dinv
// ---------------------------------------------------------------------------

#define F_IN   128
#define F_HID  32
#define F_OUT  7
#define TILE   8192
#define BSH    8              // 256 nodes per bucket
#define BNODES 256
#define HSZ    512            // LDS histogram capacity (>= NB = 391)
#define PCAP   10240          // LDS sorted-output capacity (avg bucket 8184)
#define QSH    13             // src sub-phase shift: bins of 8192 nodes
#define NQ     16             // sub-phase slots (13 used at n=100000)

typedef __attribute__((ext_vector_type(8))) short bf16x8;
typedef __attribute__((ext_vector_type(4))) float f32x4;
typedef __attribute__((ext_vector_type(4))) int   i32x4;

__device__ __forceinline__ float bf2f(unsigned short u) {
    return __uint_as_float(((unsigned int)u) << 16);
}
__device__ __forceinline__ unsigned short f2bf(float f) {
    unsigned int u = __float_as_uint(f);
    u += 0x7FFF + ((u >> 16) & 1);   // round-to-nearest-even
    return (unsigned short)(u >> 16);
}
__device__ __forceinline__ unsigned int pack2(unsigned short lo, unsigned short hi) {
    return (unsigned int)lo | ((unsigned int)hi << 16);
}
#define NTL(p) __builtin_nontemporal_load(p)

// a[k] += s * bf16row[k]  (8 fma)
__device__ __forceinline__ void acc8s(float* a, uint4 v, float s) {
    a[0] += s * bf2f((unsigned short)v.x); a[1] += s * bf2f((unsigned short)(v.x >> 16));
    a[2] += s * bf2f((unsigned short)v.y); a[3] += s * bf2f((unsigned short)(v.y >> 16));
    a[4] += s * bf2f((unsigned short)v.z); a[5] += s * bf2f((unsigned short)(v.z >> 16));
    a[6] += s * bf2f((unsigned short)v.w); a[7] += s * bf2f((unsigned short)(v.w >> 16));
}
__device__ __forceinline__ void acc8(float* a, uint4 v) {
    a[0] += bf2f((unsigned short)v.x); a[1] += bf2f((unsigned short)(v.x >> 16));
    a[2] += bf2f((unsigned short)v.y); a[3] += bf2f((unsigned short)(v.y >> 16));
    a[4] += bf2f((unsigned short)v.z); a[5] += bf2f((unsigned short)(v.z >> 16));
    a[6] += bf2f((unsigned short)v.w); a[7] += bf2f((unsigned short)(v.w >> 16));
}

// Fused launch: blocks [0,NT) = per-tile dst histogram; blocks [NT,..) = GEMM1.
// The two halves are independent (hist: dst; gemm: x,W1) and overlap.
__global__ __launch_bounds__(512)
void k_histGemm(const int* __restrict__ dst, int E, int NB, int NT,
                int* __restrict__ counts,
                const float* __restrict__ x, const float* __restrict__ W1,
                unsigned short* __restrict__ g1b, int n) {
    int t = threadIdx.x;
    if (blockIdx.x < (unsigned)NT) {
        // ---- histogram tile ----
        __shared__ int h[HSZ];
        int tile = blockIdx.x;
        for (int i = t; i < NB; i += 512) h[i] = 0;
        __syncthreads();
        int base = tile * TILE;
        int lim = base + TILE; if (lim > E) lim = E;
        int n4 = (lim - base) >> 2;
        const i32x4* d4 = (const i32x4*)(dst + base);
        for (int i = t; i < n4; i += 512) {
            i32x4 d = NTL(&d4[i]);
            atomicAdd(&h[d[0] >> BSH], 1);
            atomicAdd(&h[d[1] >> BSH], 1);
            atomicAdd(&h[d[2] >> BSH], 1);
            atomicAdd(&h[d[3] >> BSH], 1);
        }
        __syncthreads();
        for (int i = t; i < NB; i += 512) counts[tile * NB + i] = h[i];
        return;
    }
    // ---- GEMM1 tile (unscaled): g1u = bf16(x @ W1) ----
    int gb = blockIdx.x - NT;
    int wave = t >> 6;                    // 0..7
    int lane = t & 63;
    int row0 = (gb * 8 + wave) * 16;
    if (row0 >= n) return;                // n % 16 == 0
    // B-fragments straight from W1 (16KB, L2-resident)
    bf16x8 bfr[2][4];
    #pragma unroll
    for (int nt = 0; nt < 2; ++nt)
        #pragma unroll
        for (int ks = 0; ks < 4; ++ks) {
            bf16x8 w;
            #pragma unroll
            for (int j = 0; j < 8; ++j) {
                int k = ks * 32 + ((lane >> 4) << 3) + j;
                w[j] = (short)f2bf(W1[k * F_HID + nt * 16 + (lane & 15)]);
            }
            bfr[nt][ks] = w;
        }
    int arow = row0 + (lane & 15);
    const float* xr = x + (size_t)arow * F_IN + ((lane >> 4) << 3);
    f32x4 acc0 = {0.f, 0.f, 0.f, 0.f};
    f32x4 acc1 = {0.f, 0.f, 0.f, 0.f};
    #pragma unroll
    for (int ks = 0; ks < 4; ++ks) {
        f32x4 lo = NTL((const f32x4*)(xr + ks * 32));
        f32x4 hi = NTL((const f32x4*)(xr + ks * 32 + 4));
        bf16x8 a;
        a[0] = (short)f2bf(lo[0]); a[1] = (short)f2bf(lo[1]);
        a[2] = (short)f2bf(lo[2]); a[3] = (short)f2bf(lo[3]);
        a[4] = (short)f2bf(hi[0]); a[5] = (short)f2bf(hi[1]);
        a[6] = (short)f2bf(hi[2]); a[7] = (short)f2bf(hi[3]);
        acc0 = __builtin_amdgcn_mfma_f32_16x16x32_bf16(a, bfr[0][ks], acc0, 0, 0, 0);
        acc1 = __builtin_amdgcn_mfma_f32_16x16x32_bf16(a, bfr[1][ks], acc1, 0, 0, 0);
    }
    int col = lane & 15;
    #pragma unroll
    for (int rr = 0; rr < 4; ++rr) {
        int orow = row0 + ((lane >> 4) << 2) + rr;
        g1b[(size_t)orow * F_HID + col]      = f2bf(acc0[rr]);
        g1b[(size_t)orow * F_HID + col + 16] = f2bf(acc1[rr]);
    }
}

// Scan K1: block-local exclusive scan of counts (bucket-major view) ->
// tileOffset (local prefixes) + per-block sums -> bsum.
__global__ void k_scanLocal(const int* __restrict__ counts, int NSCAN, int NB, int NT,
                            int* __restrict__ tileOffset, int* __restrict__ bsum) {
    __shared__ int s[1024];
    int t = threadIdx.x;
    int idx = blockIdx.x * 1024 + t;
    int v = 0;
    if (idx < NSCAN) { int b = idx / NT, tt = idx - b * NT; v = counts[tt * NB + b]; }
    s[t] = v;
    __syncthreads();
    for (int off = 1; off < 1024; off <<= 1) {
        int a = (t >= off) ? s[t - off] : 0;
        __syncthreads();
        s[t] += a;
        __syncthreads();
    }
    if (idx < NSCAN) tileOffset[idx] = s[t] - v;   // local exclusive prefix
    if (t == 1023) bsum[blockIdx.x] = s[1023];     // block total
}

// Scan K2: each block computes its global offset from bsum and adds it.
__global__ void k_scanAdd(int* __restrict__ tileOffset, int NSCAN,
                          const int* __restrict__ bsum, int nsb) {
    __shared__ int s[1024];
    int t = threadIdx.x;
    int blk = blockIdx.x;
    s[t] = (t < blk && t < nsb) ? bsum[t] : 0;     // nsb <= 1024
    __syncthreads();
    for (int off = 512; off > 0; off >>= 1) {
        if (t < off) s[t] += s[t + off];
        __syncthreads();
    }
    int offv = s[0];
    int idx = blk * 1024 + t;
    if (idx < NSCAN) tileOffset[idx] += offv;
}

// Pass B: scatter packed (local8|src17) into per-(tile,bucket) contiguous runs.
__global__ __launch_bounds__(512)
void k_tileFill(const int* __restrict__ src, const int* __restrict__ dst,
                int E, int NB, int NT, const int* __restrict__ tileOffset,
                int* __restrict__ pairBuf) {
    __shared__ int lcur[HSZ];
    int bid = blockIdx.x;
    int xcd = bid & 7;
    int idx = bid >> 3;
    int q = NT >> 3, r = NT & 7;
    int tile = (xcd < r ? xcd * (q + 1) : r * (q + 1) + (xcd - r) * q) + idx;
    int t = threadIdx.x;
    for (int i = t; i < NB; i += 512) lcur[i] = tileOffset[i * NT + tile];
    __syncthreads();
    int base = tile * TILE;
    int lim = base + TILE; if (lim > E) lim = E;
    int n4 = (lim - base) >> 2;
    const i32x4* s4 = (const i32x4*)(src + base);
    const i32x4* d4 = (const i32x4*)(dst + base);
    for (int i = t; i < n4; i += 512) {
        i32x4 s = NTL(&s4[i]);
        i32x4 d = NTL(&d4[i]);
        #pragma unroll
        for (int k = 0; k < 4; ++k) {
            int b = d[k] >> BSH;
            int pos = atomicAdd(&lcur[b], 1);                 // LDS cursor
            pairBuf[pos] = ((d[k] & (BNODES - 1)) << 17) | s[k]; // src < 2^17
        }
    }
}

// Pass C: per-bucket CSR finish. 13-way src-ordered placement into LDS outb,
// then coalesced dump to srcSorted.
__global__ __launch_bounds__(512)
void k_bucketCSR(const int* __restrict__ pairBuf, const int* __restrict__ tileOffset,
                 int NT, int NB, int E, int n,
                 int* __restrict__ degi, int* __restrict__ cursor,
                 float* __restrict__ dinv, int* __restrict__ srcSorted) {
    __shared__ int outb[PCAP];           // 40 KB sorted output staging
    __shared__ int cntq[BNODES * NQ];    // 16 KB (node<<4 | subphase)
    __shared__ int pref[BNODES * NQ];    // 16 KB relative cursors
    __shared__ int sred[512];            // 2 KB
    int b = blockIdx.x, t = threadIdx.x;
    for (int i = t; i < BNODES * NQ; i += 512) cntq[i] = 0;
    __syncthreads();
    int bs = tileOffset[b * NT];
    int be = (b + 1 < NB) ? tileOffset[(b + 1) * NT] : E;
    int sz = be - bs;
    // pass 1: histogram over (node, src>>13)
    for (int j = bs + t; j < be; j += 512) {
        int p = pairBuf[j];
        int idx = ((p >> 17) << 4) | ((p >> QSH) & (NQ - 1));
        atomicAdd(&cntq[idx], 1);
    }
    __syncthreads();
    // exclusive scan over 4096 entries: thread t owns entries 8t..8t+7
    int loc[8];
    int base8 = t << 3;
    int sum = 0;
    #pragma unroll
    for (int k = 0; k < 8; ++k) { loc[k] = cntq[base8 + k]; sum += loc[k]; }
    sred[t] = sum;
    __syncthreads();
    for (int off = 1; off < 512; off <<= 1) {
        int a = (t >= off) ? sred[t - off] : 0;
        __syncthreads();
        sred[t] += a;
        __syncthreads();
    }
    int run = sred[t] - sum;             // exclusive prefix at entry 8t
    #pragma unroll
    for (int k = 0; k < 8; ++k) { pref[base8 + k] = run; run += loc[k]; }
    __syncthreads();
    if (t < BNODES) {
        int node = (b << BSH) + t;
        if (node < n) {
            int dsum = 0;
            #pragma unroll
            for (int k = 0; k < NQ; ++k) dsum += cntq[(t << 4) + k];
            degi[node]   = dsum;
            cursor[node] = bs + pref[t << 4];
            dinv[node]   = rsqrtf((float)dsum + 1.0f);  // +1 self-loop
        }
    }
    __syncthreads();
    // pass 2: placement into LDS (relative positions); global fallback tail
    for (int j = bs + t; j < be; j += 512) {
        int p = pairBuf[j];
        int idx = ((p >> 17) << 4) | ((p >> QSH) & (NQ - 1));
        int pos = atomicAdd(&pref[idx], 1);
        int s = p & 0x1FFFF;
        if (pos < PCAP) outb[pos] = s;
        else            srcSorted[bs + pos] = s;
    }
    __syncthreads();
    // pass 3: coalesced dump LDS -> global
    int lim = sz < PCAP ? sz : PCAP;
    for (int idx = t; idx < lim; idx += 512) srcSorted[bs + idx] = outb[idx];
}

// Gather conv1 + ReLU + tiny GEMM2 fused. g1 rows UNSCALED; dinv[s] applied
// per edge (fma, L2-resident 400KB table). 8 lanes/node: two quads walk
// interleaved edges; sub-lane f owns feats 8f..8f+7. shfl_xor(4) combine.
__global__ void k_gather1l2(const uint4* __restrict__ g1q, const int* __restrict__ srcSorted,
                            const int* __restrict__ cursor, const int* __restrict__ degi,
                            const float* __restrict__ dinv, const float* __restrict__ b1,
                            const float* __restrict__ W2, uint4* __restrict__ g2q, int n) {
    int t = threadIdx.x;
    int c = t & 7;                        // lane within node group
    int q = c >> 2;                       // quad 0/1
    int f = c & 3;                        // owns feats 8f..8f+7
    int node = blockIdx.x * 32 + (t >> 3);
    if (node >= n) return;
    int start = cursor[node];
    int end = start + degi[node];
    float di = dinv[node];
    float a[8], b[8];
    #pragma unroll
    for (int k = 0; k < 8; ++k) { a[k] = 0.f; b[k] = 0.f; }
    if (q == 0) acc8s(a, g1q[node * 4 + f], di);  // self-loop (quad 0 only)
    int j = start + q;
    for (; j + 6 < end; j += 8) {                 // 4 edges per quad per iter
        int s0 = srcSorted[j];
        int s1 = srcSorted[j + 2];
        int s2 = srcSorted[j + 4];
        int s3 = srcSorted[j + 6];
        uint4 v0 = g1q[s0 * 4 + f];
        uint4 v1 = g1q[s1 * 4 + f];
        uint4 v2 = g1q[s2 * 4 + f];
        uint4 v3 = g1q[s3 * 4 + f];
        float d0 = dinv[s0], d1 = dinv[s1], d2 = dinv[s2], d3 = dinv[s3];
        acc8s(a, v0, d0); acc8s(b, v1, d1); acc8s(a, v2, d2); acc8s(b, v3, d3);
    }
    for (; j < end; j += 2) { int s0 = srcSorted[j]; acc8s(a, g1q[s0 * 4 + f], dinv[s0]); }
    float af[8];
    #pragma unroll
    for (int k = 0; k < 8; ++k) {
        af[k] = a[k] + b[k];
        af[k] += __shfl_xor(af[k], 4, 64);        // combine quads
    }
    float h[8];
    #pragma unroll
    for (int k = 0; k < 8; ++k) {
        float v = di * af[k] + b1[8 * f + k];
        h[k] = v > 0.f ? v : 0.f;
    }
    float p[F_OUT];
    #pragma unroll
    for (int k = 0; k < F_OUT; ++k) {
        float s = 0.f;
        #pragma unroll
        for (int f8 = 0; f8 < 8; ++f8) s += h[f8] * W2[(8 * f + f8) * F_OUT + k];
        p[k] = s;
    }
    #pragma unroll
    for (int m = 1; m < 4; m <<= 1) {
        #pragma unroll
        for (int k = 0; k < F_OUT; ++k) p[k] += __shfl_xor(p[k], m, 64);
    }
    if (c == 0) {
        uint4 qv;
        qv.x = pack2(f2bf(di * p[0]), f2bf(di * p[1]));
        qv.y = pack2(f2bf(di * p[2]), f2bf(di * p[3]));
        qv.z = pack2(f2bf(di * p[4]), f2bf(di * p[5]));
        qv.w = pack2(f2bf(di * p[6]), 0);
        g2q[node] = qv;                   // 16B bf16 row (8 slots, last = 0)
    }
}

// Gather conv2 + bias + log-softmax fused. 1 lane/node, uint4 row loads,
// i32x4 index loads, softmax fully in-thread. out store nt.
__global__ void k_gather2final(const uint4* __restrict__ g2q,
                               const int* __restrict__ srcSorted,
                               const int* __restrict__ cursor, const int* __restrict__ degi,
                               const float* __restrict__ dinv, const float* __restrict__ b2,
                               float* __restrict__ out, int n) {
    int node = blockIdx.x * 256 + threadIdx.x;
    if (node >= n) return;
    int start = cursor[node];
    int end = start + degi[node];
    float A[8], B[8];
    #pragma unroll
    for (int f = 0; f < 8; ++f) { A[f] = 0.f; B[f] = 0.f; }
    acc8(A, g2q[node]);                   // self-loop init (slot 7 = 0)
    int j = start;
    while (j < end && (j & 3)) { acc8(B, g2q[srcSorted[j]]); ++j; }  // align head
    for (; j + 4 <= end; j += 4) {
        i32x4 sA = *(const i32x4*)&srcSorted[j];
        uint4 r0 = g2q[sA[0]];
        uint4 r1 = g2q[sA[1]];
        uint4 r2 = g2q[sA[2]];
        uint4 r3 = g2q[sA[3]];
        acc8(A, r0); acc8(B, r1); acc8(A, r2); acc8(B, r3);
    }
    for (; j < end; ++j) acc8(A, g2q[srcSorted[j]]);
    float di = dinv[node];
    float v[F_OUT];
    float m = -1e30f;
    #pragma unroll
    for (int k = 0; k < F_OUT; ++k) {
        v[k] = di * (A[k] + B[k]) + b2[k];
        m = fmaxf(m, v[k]);
    }
    float ssum = 0.f;
    #pragma unroll
    for (int k = 0; k < F_OUT; ++k) ssum += __expf(v[k] - m);
    float ls = __logf(ssum) + m;
    #pragma unroll
    for (int k = 0; k < F_OUT; ++k)
        __builtin_nontemporal_store(v[k] - ls, &out[node * F_OUT + k]);
}

extern "C" void kernel_launch(void* const* d_in, const int* in_sizes, int n_in,
                              void* d_out, int out_size, void* d_ws, size_t ws_size,
                              hipStream_t stream) {
    const float* x  = (const float*)d_in[0];
    const int*   ei = (const int*)d_in[1];
    const float* W1 = (const float*)d_in[2];
    const float* b1 = (const float*)d_in[3];
    const float* W2 = (const float*)d_in[4];
    const float* b2 = (const float*)d_in[5];
    float* out = (float*)d_out;

    int n = in_sizes[0] / F_IN;            // 100000
    int E = in_sizes[1] / 2;               // 3200000
    const int* src = ei;
    const int* dst = ei + E;
    int NB = (n + BNODES - 1) >> BSH;      // 391 buckets
    int NT = (E + TILE - 1) / TILE;        // 391 tiles
    int NSCAN = NB * NT;                   // 152881
    int nsb = (NSCAN + 1023) / 1024;       // 150 scan blocks
    int ngem = (n + 127) / 128;            // 782 gemm blocks (8 waves x 16 rows)

    // workspace layout (g1b aliases pairBuf: pairBuf dead after k_bucketCSR)
    int*            degi       = (int*)d_ws;                  // [n]
    int*            cursor     = degi + n;                    // [n]
    float*          dinv       = (float*)(cursor + n);        // [n]
    int*            srcSorted  = (int*)(dinv + n);            // [E]  (16B-aligned)
    int*            pairBuf    = srcSorted + E;               // [E]
    unsigned short* g1b        = (unsigned short*)(pairBuf + E); // [n*32] bf16 (SEPARATE:
                                                              // written before pairBuf dead)
    unsigned short* g2b        = g1b + (size_t)n * F_HID;     // [n*8] bf16
    int*            counts     = (int*)(g2b + (size_t)n * 8); // [NSCAN] tile-major
    int*            tileOffset = counts + NSCAN;              // [NSCAN] bucket-major
    int*            bsum       = tileOffset + NSCAN;          // [nsb]

    k_histGemm<<<NT + ngem, 512, 0, stream>>>(dst, E, NB, NT, counts, x, W1, g1b, n);
    k_scanLocal<<<nsb, 1024, 0, stream>>>(counts, NSCAN, NB, NT, tileOffset, bsum);
    k_scanAdd<<<nsb, 1024, 0, stream>>>(tileOffset, NSCAN, bsum, nsb);
    k_tileFill<<<NT, 512, 0, stream>>>(src, dst, E, NB, NT, tileOffset, pairBuf);
    k_bucketCSR<<<NB, 512, 0, stream>>>(pairBuf, tileOffset, NT, NB, E, n,
                                        degi, cursor, dinv, srcSorted);
    k_gather1l2<<<(n + 31) / 32, 256, 0, stream>>>((const uint4*)g1b, srcSorted, cursor, degi,
                                                   dinv, b1, W2, (uint4*)g2b, n);
    k_gather2final<<<(n + 255) / 256, 256, 0, stream>>>((const uint4*)g2b, srcSorted, cursor,
                                                        degi, dinv, b2, out, n);
}

// Round 19
// 140.374 us; speedup vs baseline: 1.0697x; 1.0697x over previous
//
#include <hip/hip_runtime.h>
#include <math.h>

// ---------------------------------------------------------------------------
// 2-layer GCN (PyG GCNConv) on MI355X — tiled-partition CSR + MLP-deep gather.
// g1 computed UNSCALED by the fused hist+gemm launch (overlaps the sort);
// bucketCSR pass-4 scales g1 rows in place once dinv is known, so the gather
// loop touches exactly ONE random line per edge (R17's dinv[src] regression
// reverted). 7 launches.
// out[i] = logsoftmax( dinv[i]*(g2[i] + sum_{e:dst=i} g2[src_e]) + b2 )
// g2 = dinv*( relu( dinv*(g1[i]+sum g1[src]) + b1 ) @ W2 ), g1 = (x@W1)*dinv
// ---------------------------------------------------------------------------

#define F_IN   128
#define F_HID  32
#define F_OUT  7
#define TILE   8192
#define BSH    8              // 256 nodes per bucket
#define BNODES 256
#define HSZ    512            // LDS histogram capacity (>= NB = 391)
#define PCAP   10240          // LDS sorted-output capacity (avg bucket 8184)
#define QSH    13             // src sub-phase shift: bins of 8192 nodes
#define NQ     16             // sub-phase slots (13 used at n=100000)

typedef __attribute__((ext_vector_type(8))) short bf16x8;
typedef __attribute__((ext_vector_type(4))) float f32x4;
typedef __attribute__((ext_vector_type(4))) int   i32x4;

__device__ __forceinline__ float bf2f(unsigned short u) {
    return __uint_as_float(((unsigned int)u) << 16);
}
__device__ __forceinline__ unsigned short f2bf(float f) {
    unsigned int u = __float_as_uint(f);
    u += 0x7FFF + ((u >> 16) & 1);   // round-to-nearest-even
    return (unsigned short)(u >> 16);
}
__device__ __forceinline__ unsigned int pack2(unsigned short lo, unsigned short hi) {
    return (unsigned int)lo | ((unsigned int)hi << 16);
}
#define NTL(p) __builtin_nontemporal_load(p)

// accumulate 8 bf16 (uint4) into 8 fp32
__device__ __forceinline__ void acc8(float* a, uint4 v) {
    a[0] += bf2f((unsigned short)v.x); a[1] += bf2f((unsigned short)(v.x >> 16));
    a[2] += bf2f((unsigned short)v.y); a[3] += bf2f((unsigned short)(v.y >> 16));
    a[4] += bf2f((unsigned short)v.z); a[5] += bf2f((unsigned short)(v.z >> 16));
    a[6] += bf2f((unsigned short)v.w); a[7] += bf2f((unsigned short)(v.w >> 16));
}

// Fused launch: blocks [0,NT) = per-tile dst histogram; blocks [NT,..) = GEMM1.
__global__ __launch_bounds__(512)
void k_histGemm(const int* __restrict__ dst, int E, int NB, int NT,
                int* __restrict__ counts,
                const float* __restrict__ x, const float* __restrict__ W1,
                unsigned short* __restrict__ g1b, int n) {
    int t = threadIdx.x;
    if (blockIdx.x < (unsigned)NT) {
        __shared__ int h[HSZ];
        int tile = blockIdx.x;
        for (int i = t; i < NB; i += 512) h[i] = 0;
        __syncthreads();
        int base = tile * TILE;
        int lim = base + TILE; if (lim > E) lim = E;
        int n4 = (lim - base) >> 2;
        const i32x4* d4 = (const i32x4*)(dst + base);
        for (int i = t; i < n4; i += 512) {
            i32x4 d = NTL(&d4[i]);
            atomicAdd(&h[d[0] >> BSH], 1);
            atomicAdd(&h[d[1] >> BSH], 1);
            atomicAdd(&h[d[2] >> BSH], 1);
            atomicAdd(&h[d[3] >> BSH], 1);
        }
        __syncthreads();
        for (int i = t; i < NB; i += 512) counts[tile * NB + i] = h[i];
        return;
    }
    // ---- GEMM1 tile (unscaled): g1u = bf16(x @ W1) ----
    int gb = blockIdx.x - NT;
    int wave = t >> 6;                    // 0..7
    int lane = t & 63;
    int row0 = (gb * 8 + wave) * 16;
    if (row0 >= n) return;                // n % 16 == 0
    bf16x8 bfr[2][4];
    #pragma unroll
    for (int nt = 0; nt < 2; ++nt)
        #pragma unroll
        for (int ks = 0; ks < 4; ++ks) {
            bf16x8 w;
            #pragma unroll
            for (int j = 0; j < 8; ++j) {
                int k = ks * 32 + ((lane >> 4) << 3) + j;
                w[j] = (short)f2bf(W1[k * F_HID + nt * 16 + (lane & 15)]);
            }
            bfr[nt][ks] = w;
        }
    int arow = row0 + (lane & 15);
    const float* xr = x + (size_t)arow * F_IN + ((lane >> 4) << 3);
    f32x4 acc0 = {0.f, 0.f, 0.f, 0.f};
    f32x4 acc1 = {0.f, 0.f, 0.f, 0.f};
    #pragma unroll
    for (int ks = 0; ks < 4; ++ks) {
        f32x4 lo = NTL((const f32x4*)(xr + ks * 32));
        f32x4 hi = NTL((const f32x4*)(xr + ks * 32 + 4));
        bf16x8 a;
        a[0] = (short)f2bf(lo[0]); a[1] = (short)f2bf(lo[1]);
        a[2] = (short)f2bf(lo[2]); a[3] = (short)f2bf(lo[3]);
        a[4] = (short)f2bf(hi[0]); a[5] = (short)f2bf(hi[1]);
        a[6] = (short)f2bf(hi[2]); a[7] = (short)f2bf(hi[3]);
        acc0 = __builtin_amdgcn_mfma_f32_16x16x32_bf16(a, bfr[0][ks], acc0, 0, 0, 0);
        acc1 = __builtin_amdgcn_mfma_f32_16x16x32_bf16(a, bfr[1][ks], acc1, 0, 0, 0);
    }
    int col = lane & 15;
    #pragma unroll
    for (int rr = 0; rr < 4; ++rr) {
        int orow = row0 + ((lane >> 4) << 2) + rr;
        g1b[(size_t)orow * F_HID + col]      = f2bf(acc0[rr]);
        g1b[(size_t)orow * F_HID + col + 16] = f2bf(acc1[rr]);
    }
}

// Scan K1: block-local exclusive scan (bucket-major view) + block sums.
__global__ void k_scanLocal(const int* __restrict__ counts, int NSCAN, int NB, int NT,
                            int* __restrict__ tileOffset, int* __restrict__ bsum) {
    __shared__ int s[1024];
    int t = threadIdx.x;
    int idx = blockIdx.x * 1024 + t;
    int v = 0;
    if (idx < NSCAN) { int b = idx / NT, tt = idx - b * NT; v = counts[tt * NB + b]; }
    s[t] = v;
    __syncthreads();
    for (int off = 1; off < 1024; off <<= 1) {
        int a = (t >= off) ? s[t - off] : 0;
        __syncthreads();
        s[t] += a;
        __syncthreads();
    }
    if (idx < NSCAN) tileOffset[idx] = s[t] - v;   // local exclusive prefix
    if (t == 1023) bsum[blockIdx.x] = s[1023];     // block total
}

// Scan K2: add per-block global offsets.
__global__ void k_scanAdd(int* __restrict__ tileOffset, int NSCAN,
                          const int* __restrict__ bsum, int nsb) {
    __shared__ int s[1024];
    int t = threadIdx.x;
    int blk = blockIdx.x;
    s[t] = (t < blk && t < nsb) ? bsum[t] : 0;     // nsb <= 1024
    __syncthreads();
    for (int off = 512; off > 0; off >>= 1) {
        if (t < off) s[t] += s[t + off];
        __syncthreads();
    }
    int offv = s[0];
    int idx = blk * 1024 + t;
    if (idx < NSCAN) tileOffset[idx] += offv;
}

// Pass B: scatter packed (local8|src17) into per-(tile,bucket) contiguous runs.
__global__ __launch_bounds__(512)
void k_tileFill(const int* __restrict__ src, const int* __restrict__ dst,
                int E, int NB, int NT, const int* __restrict__ tileOffset,
                int* __restrict__ pairBuf) {
    __shared__ int lcur[HSZ];
    int bid = blockIdx.x;
    int xcd = bid & 7;
    int idx = bid >> 3;
    int q = NT >> 3, r = NT & 7;
    int tile = (xcd < r ? xcd * (q + 1) : r * (q + 1) + (xcd - r) * q) + idx;
    int t = threadIdx.x;
    for (int i = t; i < NB; i += 512) lcur[i] = tileOffset[i * NT + tile];
    __syncthreads();
    int base = tile * TILE;
    int lim = base + TILE; if (lim > E) lim = E;
    int n4 = (lim - base) >> 2;
    const i32x4* s4 = (const i32x4*)(src + base);
    const i32x4* d4 = (const i32x4*)(dst + base);
    for (int i = t; i < n4; i += 512) {
        i32x4 s = NTL(&s4[i]);
        i32x4 d = NTL(&d4[i]);
        #pragma unroll
        for (int k = 0; k < 4; ++k) {
            int b = d[k] >> BSH;
            int pos = atomicAdd(&lcur[b], 1);                 // LDS cursor
            pairBuf[pos] = ((d[k] & (BNODES - 1)) << 17) | s[k]; // src < 2^17
        }
    }
}

// Pass C: per-bucket CSR finish + pass 4: scale this bucket's g1 rows by dinv.
__global__ __launch_bounds__(512)
void k_bucketCSR(const int* __restrict__ pairBuf, const int* __restrict__ tileOffset,
                 int NT, int NB, int E, int n,
                 int* __restrict__ degi, int* __restrict__ cursor,
                 float* __restrict__ dinv, int* __restrict__ srcSorted,
                 uint4* __restrict__ g1q) {
    __shared__ int outb[PCAP];           // 40 KB sorted output staging
    __shared__ int cntq[BNODES * NQ];    // 16 KB (node<<4 | subphase)
    __shared__ int pref[BNODES * NQ];    // 16 KB relative cursors
    __shared__ int sred[512];            // 2 KB
    __shared__ float sdinv[BNODES];      // 1 KB  dinv cache for pass 4
    int b = blockIdx.x, t = threadIdx.x;
    for (int i = t; i < BNODES * NQ; i += 512) cntq[i] = 0;
    __syncthreads();
    int bs = tileOffset[b * NT];
    int be = (b + 1 < NB) ? tileOffset[(b + 1) * NT] : E;
    int sz = be - bs;
    // pass 1: histogram over (node, src>>13)
    for (int j = bs + t; j < be; j += 512) {
        int p = pairBuf[j];
        int idx = ((p >> 17) << 4) | ((p >> QSH) & (NQ - 1));
        atomicAdd(&cntq[idx], 1);
    }
    __syncthreads();
    // exclusive scan over 4096 entries: thread t owns entries 8t..8t+7
    int loc[8];
    int base8 = t << 3;
    int sum = 0;
    #pragma unroll
    for (int k = 0; k < 8; ++k) { loc[k] = cntq[base8 + k]; sum += loc[k]; }
    sred[t] = sum;
    __syncthreads();
    for (int off = 1; off < 512; off <<= 1) {
        int a = (t >= off) ? sred[t - off] : 0;
        __syncthreads();
        sred[t] += a;
        __syncthreads();
    }
    int run = sred[t] - sum;             // exclusive prefix at entry 8t
    #pragma unroll
    for (int k = 0; k < 8; ++k) { pref[base8 + k] = run; run += loc[k]; }
    __syncthreads();
    if (t < BNODES) {
        int node = (b << BSH) + t;
        if (node < n) {
            int dsum = 0;
            #pragma unroll
            for (int k = 0; k < NQ; ++k) dsum += cntq[(t << 4) + k];
            float di = rsqrtf((float)dsum + 1.0f);   // +1 self-loop
            degi[node]   = dsum;
            cursor[node] = bs + pref[t << 4];
            dinv[node]   = di;
            sdinv[t]     = di;
        }
    }
    __syncthreads();
    // pass 2: placement into LDS (relative positions); global fallback tail
    for (int j = bs + t; j < be; j += 512) {
        int p = pairBuf[j];
        int idx = ((p >> 17) << 4) | ((p >> QSH) & (NQ - 1));
        int pos = atomicAdd(&pref[idx], 1);
        int s = p & 0x1FFFF;
        if (pos < PCAP) outb[pos] = s;
        else            srcSorted[bs + pos] = s;
    }
    __syncthreads();
    // pass 3: coalesced dump LDS -> global
    int lim = sz < PCAP ? sz : PCAP;
    for (int idx = t; idx < lim; idx += 512) srcSorted[bs + idx] = outb[idx];
    // pass 4: scale g1 rows (bucket-local, 16KB r/w): g1u[node] *= dinv[node]
    int nodeBase = b << BSH;
    for (int i = t; i < BNODES * 4; i += 512) {
        int node = nodeBase + (i >> 2);
        if (node < n) {
            float di = sdinv[i >> 2];
            uint4 v = g1q[(size_t)node * 4 + (i & 3)];
            uint4 o;
            o.x = pack2(f2bf(di * bf2f((unsigned short)v.x)),
                        f2bf(di * bf2f((unsigned short)(v.x >> 16))));
            o.y = pack2(f2bf(di * bf2f((unsigned short)v.y)),
                        f2bf(di * bf2f((unsigned short)(v.y >> 16))));
            o.z = pack2(f2bf(di * bf2f((unsigned short)v.z)),
                        f2bf(di * bf2f((unsigned short)(v.z >> 16))));
            o.w = pack2(f2bf(di * bf2f((unsigned short)v.w)),
                        f2bf(di * bf2f((unsigned short)(v.w >> 16))));
            g1q[(size_t)node * 4 + (i & 3)] = o;
        }
    }
}

// Gather conv1 + ReLU + tiny GEMM2 fused. g1 rows PRE-SCALED.
// 8 lanes/node: two quads walk interleaved edges; sub-lane f owns feats
// 8f..8f+7 (uint4). Quads combined via shfl_xor(4). One random line/edge.
__global__ void k_gather1l2(const uint4* __restrict__ g1q, const int* __restrict__ srcSorted,
                            const int* __restrict__ cursor, const int* __restrict__ degi,
                            const float* __restrict__ dinv, const float* __restrict__ b1,
                            const float* __restrict__ W2, uint4* __restrict__ g2q, int n) {
    int t = threadIdx.x;
    int c = t & 7;                        // lane within node group
    int q = c >> 2;                       // quad 0/1
    int f = c & 3;                        // owns feats 8f..8f+7
    int node = blockIdx.x * 32 + (t >> 3);
    if (node >= n) return;
    int start = cursor[node];
    int end = start + degi[node];
    float a[8], b[8];
    #pragma unroll
    for (int k = 0; k < 8; ++k) { a[k] = 0.f; b[k] = 0.f; }
    if (q == 0) acc8(a, g1q[node * 4 + f]);   // self-loop (quad 0 only)
    int j = start + q;
    for (; j + 6 < end; j += 8) {             // 4 edges per quad per iter
        int s0 = srcSorted[j];
        int s1 = srcSorted[j + 2];
        int s2 = srcSorted[j + 4];
        int s3 = srcSorted[j + 6];
        uint4 v0 = g1q[s0 * 4 + f];
        uint4 v1 = g1q[s1 * 4 + f];
        uint4 v2 = g1q[s2 * 4 + f];
        uint4 v3 = g1q[s3 * 4 + f];
        acc8(a, v0); acc8(b, v1); acc8(a, v2); acc8(b, v3);
    }
    for (; j < end; j += 2) acc8(a, g1q[srcSorted[j] * 4 + f]);
    float af[8];
    #pragma unroll
    for (int k = 0; k < 8; ++k) {
        af[k] = a[k] + b[k];
        af[k] += __shfl_xor(af[k], 4, 64);    // combine quads
    }
    float di = dinv[node];
    float h[8];
    #pragma unroll
    for (int k = 0; k < 8; ++k) {
        float v = di * af[k] + b1[8 * f + k];
        h[k] = v > 0.f ? v : 0.f;
    }
    float p[F_OUT];
    #pragma unroll
    for (int k = 0; k < F_OUT; ++k) {
        float s = 0.f;
        #pragma unroll
        for (int f8 = 0; f8 < 8; ++f8) s += h[f8] * W2[(8 * f + f8) * F_OUT + k];
        p[k] = s;
    }
    #pragma unroll
    for (int m = 1; m < 4; m <<= 1) {
        #pragma unroll
        for (int k = 0; k < F_OUT; ++k) p[k] += __shfl_xor(p[k], m, 64);
    }
    if (c == 0) {
        uint4 qv;
        qv.x = pack2(f2bf(di * p[0]), f2bf(di * p[1]));
        qv.y = pack2(f2bf(di * p[2]), f2bf(di * p[3]));
        qv.z = pack2(f2bf(di * p[4]), f2bf(di * p[5]));
        qv.w = pack2(f2bf(di * p[6]), 0);
        g2q[node] = qv;                   // 16B bf16 row (8 slots, last = 0)
    }
}

// Gather conv2 + bias + log-softmax fused. 1 lane/node, uint4 row loads,
// i32x4 index loads, softmax fully in-thread. out store nt.
__global__ void k_gather2final(const uint4* __restrict__ g2q,
                               const int* __restrict__ srcSorted,
                               const int* __restrict__ cursor, const int* __restrict__ degi,
                               const float* __restrict__ dinv, const float* __restrict__ b2,
                               float* __restrict__ out, int n) {
    int node = blockIdx.x * 256 + threadIdx.x;
    if (node >= n) return;
    int start = cursor[node];
    int end = start + degi[node];
    float A[8], B[8];
    #pragma unroll
    for (int f = 0; f < 8; ++f) { A[f] = 0.f; B[f] = 0.f; }
    acc8(A, g2q[node]);                   // self-loop init (slot 7 = 0)
    int j = start;
    while (j < end && (j & 3)) { acc8(B, g2q[srcSorted[j]]); ++j; }  // align head
    for (; j + 4 <= end; j += 4) {
        i32x4 sA = *(const i32x4*)&srcSorted[j];
        uint4 r0 = g2q[sA[0]];
        uint4 r1 = g2q[sA[1]];
        uint4 r2 = g2q[sA[2]];
        uint4 r3 = g2q[sA[3]];
        acc8(A, r0); acc8(B, r1); acc8(A, r2); acc8(B, r3);
    }
    for (; j < end; ++j) acc8(A, g2q[srcSorted[j]]);
    float di = dinv[node];
    float v[F_OUT];
    float m = -1e30f;
    #pragma unroll
    for (int k = 0; k < F_OUT; ++k) {
        v[k] = di * (A[k] + B[k]) + b2[k];
        m = fmaxf(m, v[k]);
    }
    float ssum = 0.f;
    #pragma unroll
    for (int k = 0; k < F_OUT; ++k) ssum += __expf(v[k] - m);
    float ls = __logf(ssum) + m;
    #pragma unroll
    for (int k = 0; k < F_OUT; ++k)
        __builtin_nontemporal_store(v[k] - ls, &out[node * F_OUT + k]);
}

extern "C" void kernel_launch(void* const* d_in, const int* in_sizes, int n_in,
                              void* d_out, int out_size, void* d_ws, size_t ws_size,
                              hipStream_t stream) {
    const float* x  = (const float*)d_in[0];
    const int*   ei = (const int*)d_in[1];
    const float* W1 = (const float*)d_in[2];
    const float* b1 = (const float*)d_in[3];
    const float* W2 = (const float*)d_in[4];
    const float* b2 = (const float*)d_in[5];
    float* out = (float*)d_out;

    int n = in_sizes[0] / F_IN;            // 100000
    int E = in_sizes[1] / 2;               // 3200000
    const int* src = ei;
    const int* dst = ei + E;
    int NB = (n + BNODES - 1) >> BSH;      // 391 buckets
    int NT = (E + TILE - 1) / TILE;        // 391 tiles
    int NSCAN = NB * NT;                   // 152881
    int nsb = (NSCAN + 1023) / 1024;       // 150 scan blocks
    int ngem = (n + 127) / 128;            // 782 gemm blocks (8 waves x 16 rows)

    // workspace layout (g1b separate from pairBuf: both live simultaneously)
    int*            degi       = (int*)d_ws;                  // [n]
    int*            cursor     = degi + n;                    // [n]
    float*          dinv       = (float*)(cursor + n);        // [n]
    int*            srcSorted  = (int*)(dinv + n);            // [E]  (16B-aligned)
    int*            pairBuf    = srcSorted + E;               // [E]
    unsigned short* g1b        = (unsigned short*)(pairBuf + E); // [n*32] bf16
    unsigned short* g2b        = g1b + (size_t)n * F_HID;     // [n*8] bf16
    int*            counts     = (int*)(g2b + (size_t)n * 8); // [NSCAN] tile-major
    int*            tileOffset = counts + NSCAN;              // [NSCAN] bucket-major
    int*            bsum       = tileOffset + NSCAN;          // [nsb]

    k_histGemm<<<NT + ngem, 512, 0, stream>>>(dst, E, NB, NT, counts, x, W1, g1b, n);
    k_scanLocal<<<nsb, 1024, 0, stream>>>(counts, NSCAN, NB, NT, tileOffset, bsum);
    k_scanAdd<<<nsb, 1024, 0, stream>>>(tileOffset, NSCAN, bsum, nsb);
    k_tileFill<<<NT, 512, 0, stream>>>(src, dst, E, NB, NT, tileOffset, pairBuf);
    k_bucketCSR<<<NB, 512, 0, stream>>>(pairBuf, tileOffset, NT, NB, E, n,
                                        degi, cursor, dinv, srcSorted, (uint4*)g1b);
    k_gather1l2<<<(n + 31) / 32, 256, 0, stream>>>((const uint4*)g1b, srcSorted, cursor, degi,
                                                   dinv, b1, W2, (uint4*)g2b, n);
    k_gather2final<<<(n + 255) / 256, 256, 0, stream>>>((const uint4*)g2b, srcSorted, cursor,
                                                        degi, dinv, b2, out, n);
}